// Round 11
// baseline (341.162 us; speedup 1.0000x reference)
//
#include <hip/hip_runtime.h>

#define HEIGHT 8
#define NXCD 8

// ---------------- prep: params + width_out + bucket boxes by image ----------------
// params[2m] = {cx, cy, s, (width-1)/2}; params[2m+1] = {ca, sa, ceil(width), img_bits}
__global__ void __launch_bounds__(256)
prep_kernel(const float* __restrict__ boxes,
            const int* __restrict__ box_indices,
            float4* __restrict__ params,
            int* __restrict__ perm,
            int* __restrict__ cnt,
            float* __restrict__ width_out,
            int M, int mw)
{
    const int m = blockIdx.x * 256 + threadIdx.x;
    if (m >= M) return;
    const float x1  = boxes[m * 5 + 0];
    const float y1  = boxes[m * 5 + 1];
    const float x2  = boxes[m * 5 + 2];
    const float y2  = boxes[m * 5 + 3];
    const float ang = boxes[m * 5 + 4];
    const float bwd = x2 - x1, bhd = y2 - y1;
    const float width = (float)HEIGHT * bwd / bhd;   // same assoc as reference
    const int b = box_indices[m];
    params[2 * m]     = make_float4((x1 + x2) * 0.5f, (y1 + y2) * 0.5f,
                                    bhd / (float)HEIGHT, (width - 1.0f) * 0.5f);
    params[2 * m + 1] = make_float4(cosf(ang), sinf(ang), ceilf(width),
                                    __int_as_float(b));
    width_out[m] = (float)mw - width;
    const int rank = atomicAdd(&cnt[b], 1);
    perm[b * M + rank] = m;
}

// ---------------- phase kernel: HW-XCD-aware L2 warm + L2-hit sampling ----------------
// Reads the REAL XCD id (HW_REG_XCC_ID, verified on MI355X) instead of assuming
// a blockIdx mapping. Blocks on XCD x warm image (phase*8+x) into their own L2
// via atomic 64KB slice tickets (sequential DRAM traffic), then pop boxes of
// that image from an atomic queue -> scattered reads hit the local L2 (~8 us
// for the whole problem per the R9 diag, vs ~35 us for L2-miss service).
// Cross-bucket stealing (d>0) keeps it correct under any dispatch/ID skew.
__global__ void __launch_bounds__(512)
phase_kernel(const float* __restrict__ images,
             const float4* __restrict__ params,
             const int* __restrict__ perm,
             const int* __restrict__ cnt,
             int* __restrict__ pop,
             int* __restrict__ warm,
             float* __restrict__ crops,
             int Himg, int Wimg, int M, int N, int phase)
{
    __shared__ int sh_t;
    const int tid = threadIdx.x;
    int xcc;
    asm volatile("s_getreg_b32 %0, hwreg(HW_REG_XCC_ID)" : "=s"(xcc));
    xcc &= (NXCD - 1);
    const size_t imgsz = (size_t)Himg * Wimg * 3;

    for (int d = 0; d < NXCD; ++d) {
        const int x = (xcc + d) & (NXCD - 1);
        const int img_idx = phase * NXCD + x;
        if (img_idx >= N) continue;
        const float* img = images + (size_t)img_idx * imgsz;

        if (d == 0) {
            // ---- warm MY XCD's L2 with MY image: 64KB ticketed slices ----
            const float4* im4 = (const float4*)img;
            const int nslice = ((int)(imgsz >> 2)) >> 12;   // 4096 float4 per slice
            for (;;) {
                if (tid == 0) sh_t = atomicAdd(&warm[img_idx], 1);
                __syncthreads();
                const int t = sh_t;
                __syncthreads();
                if (t >= nslice) break;
                float acc = 0.0f;
                #pragma unroll
                for (int k = 0; k < 8; ++k) {
                    const float4 v = im4[(size_t)t * 4096 + k * 512 + tid];
                    acc += v.x + v.y + v.z + v.w;
                }
                asm volatile("" :: "v"(acc));   // keep warming loads live
            }
        }

        // ---- pop boxes of this image (self-balancing atomic queue) ----
        const int nbox = cnt[img_idx];
        for (;;) {
            if (tid == 0) sh_t = atomicAdd(&pop[img_idx], 1);
            __syncthreads();
            const int p = sh_t;
            __syncthreads();
            if (p >= nbox) break;
            const int m = perm[img_idx * M + p];

            const float4 pA = params[2 * m];      // cx, cy, s, (width-1)/2
            const float4 pB = params[2 * m + 1];  // ca, sa, ceil(width), img_bits
            const int i = tid >> 6;               // mw==64 fast path
            const int j = tid & 63;

            const float dx = pA.z * ((float)j - pA.w);
            const float dy = pA.z * ((float)i - ((float)HEIGHT - 1.0f) * 0.5f);
            const float sx = pA.x + pB.x * dx - pB.y * dy;
            const float sy = pA.y + pB.y * dx + pB.x * dy;

            float v0 = 0.0f, v1 = 0.0f, v2 = 0.0f;
            const bool valid = ((float)j < pB.z) &&
                               (sx >= 0.0f) && (sx <= (float)(Wimg - 1)) &&
                               (sy >= 0.0f) && (sy <= (float)(Himg - 1));
            if (valid) {
                const float x0 = floorf(sx);
                const float y0 = floorf(sy);
                const int x0i = (int)x0;
                const int y0i = (int)y0;
                const int xb  = min(x0i, Wimg - 2);
                const int yb  = min(y0i, Himg - 2);
                // clamped => clamped texel's weight is exactly 0; fold into fx/fy
                const float fx = (x0i == xb) ? (sx - x0) : 1.0f;
                const float fy = (y0i == yb) ? (sy - y0) : 1.0f;

                const float* r0 = img + ((size_t)yb * Wimg + xb) * 3;
                const float* r1 = r0 + (size_t)Wimg * 3;
                float s0[6], s1[6];
                __builtin_memcpy(s0, r0, 24);
                __builtin_memcpy(s1, r1, 24);

                const float w00 = (1.0f - fx) * (1.0f - fy);
                const float w01 = fx * (1.0f - fy);
                const float w10 = (1.0f - fx) * fy;
                const float w11 = fx * fy;

                v0 = s0[0] * w00 + s0[3] * w01 + s1[0] * w10 + s1[3] * w11;
                v1 = s0[1] * w00 + s0[4] * w01 + s1[1] * w10 + s1[4] * w11;
                v2 = s0[2] * w00 + s0[5] * w01 + s1[2] * w10 + s1[5] * w11;
            }
            // nontemporal: don't let 24.6 MB/phase of writes evict the image
            float* o = crops + ((size_t)m * (HEIGHT * 64) + (size_t)tid) * 3;
            __builtin_nontemporal_store(v0, o + 0);
            __builtin_nontemporal_store(v1, o + 1);
            __builtin_nontemporal_store(v2, o + 2);
        }
    }
}

// ---------------- generic fallback (exact R4 kernel, 37.1 us) ----------------
__global__ void __launch_bounds__(512)
roi_generic_kernel(const float* __restrict__ images,
                   const float* __restrict__ boxes,
                   const int* __restrict__ box_indices,
                   float* __restrict__ crops,
                   float* __restrict__ width_out,
                   int max_width, int Himg, int Wimg)
{
    const int m   = blockIdx.x;
    const int tid = threadIdx.x;
    const int mw  = max_width;
    const int i   = tid / mw;
    const int j   = tid - i * mw;

    const float x1  = boxes[m * 5 + 0];
    const float y1  = boxes[m * 5 + 1];
    const float x2  = boxes[m * 5 + 2];
    const float y2  = boxes[m * 5 + 3];
    const float ang = boxes[m * 5 + 4];
    const float bwd = x2 - x1, bhd = y2 - y1;
    const float width = (float)HEIGHT * bwd / bhd;
    const float cx = (x1 + x2) * 0.5f;
    const float cy = (y1 + y2) * 0.5f;
    const float s  = bhd / (float)HEIGHT;
    const float ca = cosf(ang);
    const float sa = sinf(ang);
    if (tid == 0) width_out[m] = (float)mw - width;

    const float dx = s * ((float)j - (width - 1.0f) * 0.5f);
    const float dy = s * ((float)i - ((float)HEIGHT - 1.0f) * 0.5f);
    const float sx = cx + ca * dx - sa * dy;
    const float sy = cy + sa * dx + ca * dy;

    float v0 = 0.0f, v1 = 0.0f, v2 = 0.0f;
    const bool valid = ((float)j < ceilf(width)) &&
                       (sx >= 0.0f) && (sx <= (float)(Wimg - 1)) &&
                       (sy >= 0.0f) && (sy <= (float)(Himg - 1));
    if (valid) {
        const float x0 = floorf(sx);
        const float y0 = floorf(sy);
        const int x0i = (int)x0;
        const int y0i = (int)y0;
        const int xb  = min(x0i, Wimg - 2);
        const int yb  = min(y0i, Himg - 2);
        const float fx = (x0i == xb) ? (sx - x0) : 1.0f;
        const float fy = (y0i == yb) ? (sy - y0) : 1.0f;
        const int b = box_indices[m];
        const float* img = images + (size_t)b * Himg * Wimg * 3;
        const float* r0  = img + ((size_t)yb * Wimg + xb) * 3;
        const float* r1  = r0 + (size_t)Wimg * 3;
        float s0[6], s1[6];
        __builtin_memcpy(s0, r0, 24);
        __builtin_memcpy(s1, r1, 24);
        const float w00 = (1.0f - fx) * (1.0f - fy);
        const float w01 = fx * (1.0f - fy);
        const float w10 = (1.0f - fx) * fy;
        const float w11 = fx * fy;
        v0 = s0[0] * w00 + s0[3] * w01 + s1[0] * w10 + s1[3] * w11;
        v1 = s0[1] * w00 + s0[4] * w01 + s1[1] * w10 + s1[4] * w11;
        v2 = s0[2] * w00 + s0[5] * w01 + s1[2] * w10 + s1[5] * w11;
    }
    float* o = crops + ((size_t)(m * HEIGHT + i) * mw + j) * 3;
    o[0] = v0; o[1] = v1; o[2] = v2;
}

extern "C" void kernel_launch(void* const* d_in, const int* in_sizes, int n_in,
                              void* d_out, int out_size, void* d_ws, size_t ws_size,
                              hipStream_t stream) {
    const float* images      = (const float*)d_in[0];
    const float* boxes       = (const float*)d_in[2];
    const int*   box_indices = (const int*)d_in[3];

    const int M  = in_sizes[3];                       // 8192 boxes
    const int mw = (out_size - M) / (M * HEIGHT * 3); // max_width (=64)
    const int Himg = 512, Wimg = 512;
    const int N  = in_sizes[0] / (Himg * Wimg * 3);   // 16 images

    float* crops     = (float*)d_out;
    float* width_out = crops + (size_t)M * HEIGHT * mw * 3;

    // ws layout: params (2M float4, 256KB) | perm (N*M int) | counters @1MB
    const size_t ctr_off = 1u << 20;
    const size_t need = ctr_off + 3 * 32 * sizeof(int);
    const bool fits = ((size_t)2 * M * sizeof(float4) + (size_t)N * M * sizeof(int)
                       <= ctr_off) && (ws_size >= need) && (N <= 32);

    if (mw == 64 && fits) {
        float4* params = (float4*)d_ws;
        int*    perm   = (int*)((char*)d_ws + (size_t)2 * M * sizeof(float4));
        int*    cnt    = (int*)((char*)d_ws + ctr_off);
        int*    pop    = cnt + 32;
        int*    warm   = pop + 32;

        hipMemsetAsync(cnt, 0, 3 * 32 * sizeof(int), stream);
        prep_kernel<<<(M + 255) / 256, 256, 0, stream>>>(
            boxes, box_indices, params, perm, cnt, width_out, M, mw);

        const int phases = (N + NXCD - 1) / NXCD;     // 2 for N=16
        for (int p = 0; p < phases; ++p) {
            phase_kernel<<<1024, 512, 0, stream>>>(
                images, params, perm, cnt, pop, warm, crops,
                Himg, Wimg, M, N, p);
        }
    } else {
        roi_generic_kernel<<<M, HEIGHT * mw, 0, stream>>>(
            images, boxes, box_indices, crops, width_out, mw, Himg, Wimg);
    }
}

// Round 12
// 37.228 us; speedup vs baseline: 9.1641x; 9.1641x over previous
//
#include <hip/hip_runtime.h>

#define HEIGHT 8

// One block per box, 512 threads: wave = one output row (i = tid/64),
// lane = column j. Per valid sample: TWO 24-byte row-segment loads
// (dwordx4 + dwordx2 each) covering both x-pixels x 3 channels. Border
// clamp folded into fx/fy via the "clamped => fractional weight is 0"
// identity, so all register indexing is compile-time constant (no scratch).
//
// Ceiling note (R10 ablation): the cold scattered gather of ~740K distinct
// 64B lines services at ~0.055 lines/cy/CU => ~35 us irreducible; this
// kernel = 37.1 us with stores overlapped. L3-prefetch (R7), phased
// per-XCD L2 warming (R8), deep per-wave MLP (R9), and HW-XCD-id work
// queues (R11) were all measured null or regressions.
__global__ void __launch_bounds__(512)
roi_rotate_kernel(const float* __restrict__ images,
                  const float* __restrict__ boxes,
                  const int* __restrict__ box_indices,
                  float* __restrict__ crops,
                  float* __restrict__ width_out,
                  int max_width, int Himg, int Wimg)
{
    const int m   = blockIdx.x;
    const int tid = threadIdx.x;
    const int mw  = max_width;
    const int i   = tid / mw;
    const int j   = tid - i * mw;

    // Block-uniform box params -> scalar loads.
    const float x1  = boxes[m * 5 + 0];
    const float y1  = boxes[m * 5 + 1];
    const float x2  = boxes[m * 5 + 2];
    const float y2  = boxes[m * 5 + 3];
    const float ang = boxes[m * 5 + 4];
    const float bwd = x2 - x1, bhd = y2 - y1;
    const float width = (float)HEIGHT * bwd / bhd;   // same assoc as reference
    const float cx = (x1 + x2) * 0.5f;
    const float cy = (y1 + y2) * 0.5f;
    const float s  = bhd / (float)HEIGHT;
    const float ca = cosf(ang);
    const float sa = sinf(ang);
    if (tid == 0) width_out[m] = (float)mw - width;

    const float dx = s * ((float)j - (width - 1.0f) * 0.5f);
    const float dy = s * ((float)i - ((float)HEIGHT - 1.0f) * 0.5f);
    const float sx = cx + ca * dx - sa * dy;
    const float sy = cy + sa * dx + ca * dy;

    float v0 = 0.0f, v1 = 0.0f, v2 = 0.0f;

    const bool valid = ((float)j < ceilf(width)) &&
                       (sx >= 0.0f) && (sx <= (float)(Wimg - 1)) &&
                       (sy >= 0.0f) && (sy <= (float)(Himg - 1));

    if (valid) {
        const float x0 = floorf(sx);   // in [0, W-1] given valid
        const float y0 = floorf(sy);
        const int x0i = (int)x0;
        const int y0i = (int)y0;
        const int xb  = min(x0i, Wimg - 2);
        const int yb  = min(y0i, Himg - 2);
        // clamped => the clamped texel's fractional weight is exactly 0,
        // so shift full weight onto the in-segment element (indices stay static)
        const float fx = (x0i == xb) ? (sx - x0) : 1.0f;
        const float fy = (y0i == yb) ? (sy - y0) : 1.0f;

        const int b = box_indices[m];
        const float* img = images + (size_t)b * Himg * Wimg * 3;
        const float* r0  = img + ((size_t)yb * Wimg + xb) * 3;
        const float* r1  = r0 + (size_t)Wimg * 3;
        float s0[6], s1[6];
        __builtin_memcpy(s0, r0, 24);   // 2 px x 3 ch, row yb
        __builtin_memcpy(s1, r1, 24);   // 2 px x 3 ch, row yb+1

        const float w00 = (1.0f - fx) * (1.0f - fy);
        const float w01 = fx * (1.0f - fy);
        const float w10 = (1.0f - fx) * fy;
        const float w11 = fx * fy;

        v0 = s0[0] * w00 + s0[3] * w01 + s1[0] * w10 + s1[3] * w11;
        v1 = s0[1] * w00 + s0[4] * w01 + s1[1] * w10 + s1[4] * w11;
        v2 = s0[2] * w00 + s0[5] * w01 + s1[2] * w10 + s1[5] * w11;
    }

    // Direct store: 64 lanes x 12B contiguous per wave -> coalesced.
    float* o = crops + ((size_t)(m * HEIGHT + i) * mw + j) * 3;
    o[0] = v0; o[1] = v1; o[2] = v2;
}

extern "C" void kernel_launch(void* const* d_in, const int* in_sizes, int n_in,
                              void* d_out, int out_size, void* d_ws, size_t ws_size,
                              hipStream_t stream) {
    const float* images      = (const float*)d_in[0];
    const float* boxes       = (const float*)d_in[2];
    const int*   box_indices = (const int*)d_in[3];

    const int M  = in_sizes[3];                       // 8192 boxes
    const int mw = (out_size - M) / (M * HEIGHT * 3); // max_width (=64)
    const int Himg = 512, Wimg = 512;

    float* crops     = (float*)d_out;
    float* width_out = crops + (size_t)M * HEIGHT * mw * 3;

    dim3 block(HEIGHT * mw);   // 512 threads = one box
    dim3 grid(M);
    roi_rotate_kernel<<<grid, block, 0, stream>>>(images, boxes, box_indices,
                                                  crops, width_out, mw, Himg, Wimg);
}